// Round 1
// baseline (171.542 us; speedup 1.0000x reference)
//
#include <hip/hip_runtime.h>

// MatchingLoss: out = 1000 * mean_b f( mean_n(||plid-img||) - mean_n(||org-img||) ) / denom
// denom = max(1080,1440) = 1440. f(d) = ((1+5*relu(-d))*d + 5*relu(d)) / (1+|d|)
// Memory-bound: 3 x 51.2 MB fp32 reads. Strategy: float4 loads (2 points/load),
// per-thread accumulate of (d1 - d2) per point (avoids cancellation of two big
// sums), wave64 shuffle reduce, one atomicAdd per block into ws[b].

#define ML_B 64
#define ML_N 100000
#define ML_DENOM 1440.0f
#define ML_F4_PER_BATCH (ML_N * 2 / 4)   // 50000 float4 per batch row
#define ML_BLOCKS_PER_BATCH 32           // power of 2 -> shift/mask indexing
#define ML_BLOCK 256

__global__ __launch_bounds__(ML_BLOCK) void ml_partial_kernel(
    const float4* __restrict__ img,
    const float4* __restrict__ plid,
    const float4* __restrict__ org,
    float* __restrict__ ws)
{
    const int b   = blockIdx.x >> 5;          // / ML_BLOCKS_PER_BATCH
    const int blk = blockIdx.x & 31;          // % ML_BLOCKS_PER_BATCH
    const long base = (long)b * ML_F4_PER_BATCH;

    float acc = 0.0f;
    const int stride = ML_BLOCKS_PER_BATCH * ML_BLOCK;  // 8192
    for (int i = blk * ML_BLOCK + threadIdx.x; i < ML_F4_PER_BATCH; i += stride) {
        float4 a = img[base + i];   // (x0,y0,x1,y1) two points
        float4 p = plid[base + i];
        float4 o = org[base + i];
        float dx1 = p.x - a.x, dy1 = p.y - a.y;
        float dx2 = p.z - a.z, dy2 = p.w - a.w;
        float ex1 = o.x - a.x, ey1 = o.y - a.y;
        float ex2 = o.z - a.z, ey2 = o.w - a.w;
        acc += sqrtf(dx1 * dx1 + dy1 * dy1) - sqrtf(ex1 * ex1 + ey1 * ey1);
        acc += sqrtf(dx2 * dx2 + dy2 * dy2) - sqrtf(ex2 * ex2 + ey2 * ey2);
    }

    // wave64 shuffle reduce
    #pragma unroll
    for (int off = 32; off > 0; off >>= 1)
        acc += __shfl_down(acc, off, 64);

    __shared__ float sdata[ML_BLOCK / 64];
    const int lane = threadIdx.x & 63;
    const int wave = threadIdx.x >> 6;
    if (lane == 0) sdata[wave] = acc;
    __syncthreads();
    if (threadIdx.x == 0) {
        float s = sdata[0] + sdata[1] + sdata[2] + sdata[3];
        atomicAdd(&ws[b], s);   // device-scope by default on CDNA
    }
}

__global__ void ml_final_kernel(const float* __restrict__ ws,
                                float* __restrict__ out)
{
    // one wave of 64 lanes, lane b handles batch b
    const int b = threadIdx.x;
    float s = ws[b];
    // diff = (sum of per-point (d1-d2)) / N / denom
    float diff = s * (1.0f / ((float)ML_N * ML_DENOM));
    float reward  = (1.0f + 5.0f * fmaxf(-diff, 0.0f)) * diff;
    float penalty = 5.0f * fmaxf(diff, 0.0f);
    float v = (reward + penalty) / (1.0f + fabsf(diff));

    #pragma unroll
    for (int off = 32; off > 0; off >>= 1)
        v += __shfl_down(v, off, 64);

    if (b == 0) out[0] = 1000.0f * v * (1.0f / (float)ML_B);
}

extern "C" void kernel_launch(void* const* d_in, const int* in_sizes, int n_in,
                              void* d_out, int out_size, void* d_ws, size_t ws_size,
                              hipStream_t stream) {
    const float4* img  = (const float4*)d_in[0];  // img_points (B,N,2)
    const float4* plid = (const float4*)d_in[1];  // projected_lid_points (B,N,2)
    // d_in[2] = mat_reg_loss (B,) -- unused by the reference
    const float4* org  = (const float4*)d_in[3];  // lid_cents_proj_Org (B,N,2)
    float* ws  = (float*)d_ws;
    float* out = (float*)d_out;

    // ws is re-poisoned to 0xAA before every timed launch -> zero the 64
    // per-batch accumulators (async memset is graph-capture safe).
    hipMemsetAsync(ws, 0, ML_B * sizeof(float), stream);

    ml_partial_kernel<<<ML_B * ML_BLOCKS_PER_BATCH, ML_BLOCK, 0, stream>>>(
        img, plid, org, ws);
    ml_final_kernel<<<1, 64, 0, stream>>>(ws, out);
}

// Round 2
// 170.377 us; speedup vs baseline: 1.0068x; 1.0068x over previous
//
#include <hip/hip_runtime.h>

// MatchingLoss: out = 1000 * mean_b f( mean_n(||plid-img||) - mean_n(||org-img||) ) / denom
// f(d) = ((1+5*relu(-d))*d + 5*relu(d)) / (1+|d|), denom = 1440.
//
// R1 finding: latency-bound, not BW-bound (warm L3-resident replays also 57us;
// VGPR=20 -> only 3 loads in flight). Fix: 4-wide manual unroll -> 12
// independent float4 loads in flight per thread; compile-time trip count.
// Per-block partials to distinct ws slots (no atomic, no memset node).

#define ML_B 64
#define ML_N 100000
#define ML_DENOM 1440.0f
#define ML_F4_PER_BATCH (ML_N * 2 / 4)   // 50000 float4 per batch row
#define ML_BPB 16                        // blocks per batch (power of 2)
#define ML_BLOCK 256
#define ML_TPB (ML_BPB * ML_BLOCK)       // 4096 threads per batch
#define ML_FULL_K 12                     // 12 * 4096 = 49152 full strided steps
#define ML_TAIL (ML_F4_PER_BATCH - ML_FULL_K * ML_TPB)  // 848

__device__ inline float pair_term(float4 a, float4 p, float4 o) {
    float dx1 = p.x - a.x, dy1 = p.y - a.y;
    float dx2 = p.z - a.z, dy2 = p.w - a.w;
    float ex1 = o.x - a.x, ey1 = o.y - a.y;
    float ex2 = o.z - a.z, ey2 = o.w - a.w;
    return sqrtf(dx1 * dx1 + dy1 * dy1) - sqrtf(ex1 * ex1 + ey1 * ey1)
         + sqrtf(dx2 * dx2 + dy2 * dy2) - sqrtf(ex2 * ex2 + ey2 * ey2);
}

__global__ __launch_bounds__(ML_BLOCK) void ml_partial_kernel(
    const float4* __restrict__ img,
    const float4* __restrict__ plid,
    const float4* __restrict__ org,
    float* __restrict__ ws)
{
    const int b   = blockIdx.x >> 4;          // / ML_BPB
    const int blk = blockIdx.x & 15;          // % ML_BPB
    const long base = (long)b * ML_F4_PER_BATCH;
    const int pos = blk * ML_BLOCK + threadIdx.x;   // 0..4095

    const float4* __restrict__ ib = img  + base;
    const float4* __restrict__ pb = plid + base;
    const float4* __restrict__ ob = org  + base;

    float acc = 0.0f;
    #pragma unroll
    for (int k = 0; k < ML_FULL_K; k += 4) {
        // 12 independent 16B loads in flight before any consumption
        float4 a0 = ib[pos + (k + 0) * ML_TPB];
        float4 a1 = ib[pos + (k + 1) * ML_TPB];
        float4 a2 = ib[pos + (k + 2) * ML_TPB];
        float4 a3 = ib[pos + (k + 3) * ML_TPB];
        float4 p0 = pb[pos + (k + 0) * ML_TPB];
        float4 p1 = pb[pos + (k + 1) * ML_TPB];
        float4 p2 = pb[pos + (k + 2) * ML_TPB];
        float4 p3 = pb[pos + (k + 3) * ML_TPB];
        float4 o0 = ob[pos + (k + 0) * ML_TPB];
        float4 o1 = ob[pos + (k + 1) * ML_TPB];
        float4 o2 = ob[pos + (k + 2) * ML_TPB];
        float4 o3 = ob[pos + (k + 3) * ML_TPB];
        acc += pair_term(a0, p0, o0);
        acc += pair_term(a1, p1, o1);
        acc += pair_term(a2, p2, o2);
        acc += pair_term(a3, p3, o3);
    }
    if (pos < ML_TAIL) {
        const int idx = ML_FULL_K * ML_TPB + pos;
        acc += pair_term(ib[idx], pb[idx], ob[idx]);
    }

    // wave64 shuffle reduce
    #pragma unroll
    for (int off = 32; off > 0; off >>= 1)
        acc += __shfl_down(acc, off, 64);

    __shared__ float sdata[ML_BLOCK / 64];
    const int lane = threadIdx.x & 63;
    const int wave = threadIdx.x >> 6;
    if (lane == 0) sdata[wave] = acc;
    __syncthreads();
    if (threadIdx.x == 0)
        ws[blockIdx.x] = sdata[0] + sdata[1] + sdata[2] + sdata[3];
}

__global__ __launch_bounds__(1024) void ml_final_kernel(
    const float* __restrict__ ws, float* __restrict__ out)
{
    // 1024 partials: thread t owns partial t; batch = t>>4 (16 partials/batch,
    // contiguous lanes, so a 16-wide shuffle sum lands the batch total).
    const int t = threadIdx.x;
    float v = ws[t];
    v += __shfl_down(v, 8, 16);
    v += __shfl_down(v, 4, 16);
    v += __shfl_down(v, 2, 16);
    v += __shfl_down(v, 1, 16);

    float f = 0.0f;
    if ((t & 15) == 0) {
        float diff = v * (1.0f / ((float)ML_N * ML_DENOM));
        float reward  = (1.0f + 5.0f * fmaxf(-diff, 0.0f)) * diff;
        float penalty = 5.0f * fmaxf(diff, 0.0f);
        f = (reward + penalty) / (1.0f + fabsf(diff));
    }

    // block sum of f (16 waves)
    #pragma unroll
    for (int off = 32; off > 0; off >>= 1)
        f += __shfl_down(f, off, 64);

    __shared__ float s[16];
    if ((t & 63) == 0) s[t >> 6] = f;
    __syncthreads();
    if (t < 16) {
        float x = s[t];
        x += __shfl_down(x, 8, 16);
        x += __shfl_down(x, 4, 16);
        x += __shfl_down(x, 2, 16);
        x += __shfl_down(x, 1, 16);
        if (t == 0) out[0] = (1000.0f / (float)ML_B) * x;
    }
}

extern "C" void kernel_launch(void* const* d_in, const int* in_sizes, int n_in,
                              void* d_out, int out_size, void* d_ws, size_t ws_size,
                              hipStream_t stream) {
    const float4* img  = (const float4*)d_in[0];  // img_points (B,N,2)
    const float4* plid = (const float4*)d_in[1];  // projected_lid_points (B,N,2)
    // d_in[2] = mat_reg_loss (B,) -- unused by the reference
    const float4* org  = (const float4*)d_in[3];  // lid_cents_proj_Org (B,N,2)
    float* ws  = (float*)d_ws;                    // 1024 per-block partials
    float* out = (float*)d_out;

    ml_partial_kernel<<<ML_B * ML_BPB, ML_BLOCK, 0, stream>>>(img, plid, org, ws);
    ml_final_kernel<<<1, 1024, 0, stream>>>(ws, out);
}

// Round 4
// 154.701 us; speedup vs baseline: 1.1089x; 1.1013x over previous
//
#include <hip/hip_runtime.h>

// MatchingLoss: out = 1000 * mean_b f( mean_n(||plid-img||) - mean_n(||org-img||) ) / denom
// f(d) = ((1+5*relu(-d))*d + 5*relu(d)) / (1+|d|), denom = 1440.
//
// R2 post-mortem: compiler re-serialized the unrolled loads (VGPR=28 -> ~1
// triplet in flight/wave); stream runs at 2.67 TB/s vs ~5-6 achievable.
// R3 failed to compile: __builtin_nontemporal_load needs a NATIVE vector
// type, not HIP_vector_type. R4: ext_vector_type(4) float + launch_bounds
// (256,2) so a depth-6 batch (18 independent dwordx4 nt-loads, ~72 data
// VGPRs) actually stays in flight.

typedef float f4 __attribute__((ext_vector_type(4)));

#define ML_B 64
#define ML_N 100000
#define ML_DENOM 1440.0f
#define ML_F4_PER_BATCH (ML_N * 2 / 4)   // 50000 float4 per batch row
#define ML_BPB 16                        // blocks per batch (power of 2)
#define ML_BLOCK 256
#define ML_TPB (ML_BPB * ML_BLOCK)       // 4096 threads per batch
#define ML_FULL_K 12                     // 12 * 4096 = 49152 full strided steps
#define ML_TAIL (ML_F4_PER_BATCH - ML_FULL_K * ML_TPB)  // 848
#define ML_DEPTH 6                       // triplets in flight per wave

__device__ inline float pair_term(f4 a, f4 p, f4 o) {
    float dx1 = p.x - a.x, dy1 = p.y - a.y;
    float dx2 = p.z - a.z, dy2 = p.w - a.w;
    float ex1 = o.x - a.x, ey1 = o.y - a.y;
    float ex2 = o.z - a.z, ey2 = o.w - a.w;
    return sqrtf(dx1 * dx1 + dy1 * dy1) - sqrtf(ex1 * ex1 + ey1 * ey1)
         + sqrtf(dx2 * dx2 + dy2 * dy2) - sqrtf(ex2 * ex2 + ey2 * ey2);
}

__global__ __launch_bounds__(ML_BLOCK, 2) void ml_partial_kernel(
    const f4* __restrict__ img,
    const f4* __restrict__ plid,
    const f4* __restrict__ org,
    float* __restrict__ ws)
{
    const int b   = blockIdx.x >> 4;          // / ML_BPB
    const int blk = blockIdx.x & 15;          // % ML_BPB
    const long base = (long)b * ML_F4_PER_BATCH;
    const int pos = blk * ML_BLOCK + threadIdx.x;   // 0..4095

    const f4* __restrict__ ib = img  + base;
    const f4* __restrict__ pb = plid + base;
    const f4* __restrict__ ob = org  + base;

    float acc = 0.0f;
    #pragma unroll
    for (int k = 0; k < ML_FULL_K; k += ML_DEPTH) {
        f4 A[ML_DEPTH], P[ML_DEPTH], O[ML_DEPTH];
        // 18 independent 16B non-temporal loads before any consumption
        #pragma unroll
        for (int j = 0; j < ML_DEPTH; ++j)
            A[j] = __builtin_nontemporal_load(&ib[pos + (k + j) * ML_TPB]);
        #pragma unroll
        for (int j = 0; j < ML_DEPTH; ++j)
            P[j] = __builtin_nontemporal_load(&pb[pos + (k + j) * ML_TPB]);
        #pragma unroll
        for (int j = 0; j < ML_DEPTH; ++j)
            O[j] = __builtin_nontemporal_load(&ob[pos + (k + j) * ML_TPB]);
        #pragma unroll
        for (int j = 0; j < ML_DEPTH; ++j)
            acc += pair_term(A[j], P[j], O[j]);
    }
    if (pos < ML_TAIL) {
        const int idx = ML_FULL_K * ML_TPB + pos;
        acc += pair_term(__builtin_nontemporal_load(&ib[idx]),
                         __builtin_nontemporal_load(&pb[idx]),
                         __builtin_nontemporal_load(&ob[idx]));
    }

    // wave64 shuffle reduce
    #pragma unroll
    for (int off = 32; off > 0; off >>= 1)
        acc += __shfl_down(acc, off, 64);

    __shared__ float sdata[ML_BLOCK / 64];
    const int lane = threadIdx.x & 63;
    const int wave = threadIdx.x >> 6;
    if (lane == 0) sdata[wave] = acc;
    __syncthreads();
    if (threadIdx.x == 0)
        ws[blockIdx.x] = sdata[0] + sdata[1] + sdata[2] + sdata[3];
}

__global__ __launch_bounds__(1024) void ml_final_kernel(
    const float* __restrict__ ws, float* __restrict__ out)
{
    // 1024 partials: thread t owns partial t; batch = t>>4 (16 partials/batch,
    // contiguous lanes, so a 16-wide shuffle sum lands the batch total).
    const int t = threadIdx.x;
    float v = ws[t];
    v += __shfl_down(v, 8, 16);
    v += __shfl_down(v, 4, 16);
    v += __shfl_down(v, 2, 16);
    v += __shfl_down(v, 1, 16);

    float f = 0.0f;
    if ((t & 15) == 0) {
        float diff = v * (1.0f / ((float)ML_N * ML_DENOM));
        float reward  = (1.0f + 5.0f * fmaxf(-diff, 0.0f)) * diff;
        float penalty = 5.0f * fmaxf(diff, 0.0f);
        f = (reward + penalty) / (1.0f + fabsf(diff));
    }

    // block sum of f (16 waves)
    #pragma unroll
    for (int off = 32; off > 0; off >>= 1)
        f += __shfl_down(f, off, 64);

    __shared__ float s[16];
    if ((t & 63) == 0) s[t >> 6] = f;
    __syncthreads();
    if (t < 16) {
        float x = s[t];
        x += __shfl_down(x, 8, 16);
        x += __shfl_down(x, 4, 16);
        x += __shfl_down(x, 2, 16);
        x += __shfl_down(x, 1, 16);
        if (t == 0) out[0] = (1000.0f / (float)ML_B) * x;
    }
}

extern "C" void kernel_launch(void* const* d_in, const int* in_sizes, int n_in,
                              void* d_out, int out_size, void* d_ws, size_t ws_size,
                              hipStream_t stream) {
    const f4* img  = (const f4*)d_in[0];  // img_points (B,N,2)
    const f4* plid = (const f4*)d_in[1];  // projected_lid_points (B,N,2)
    // d_in[2] = mat_reg_loss (B,) -- unused by the reference
    const f4* org  = (const f4*)d_in[3];  // lid_cents_proj_Org (B,N,2)
    float* ws  = (float*)d_ws;            // 1024 per-block partials
    float* out = (float*)d_out;

    ml_partial_kernel<<<ML_B * ML_BPB, ML_BLOCK, 0, stream>>>(img, plid, org, ws);
    ml_final_kernel<<<1, 1024, 0, stream>>>(ws, out);
}